// Round 11
// baseline (186.585 us; speedup 1.0000x reference)
//
#include <hip/hip_runtime.h>

// mp: [1, 21, 16, 256, 256] fp32
#define CC   21
#define DD   16
#define HH   256
#define WW   256
#define HWP  (HH * WW)      // 65536
#define DHW  (DD * HWP)     // 1048576

typedef float f4a __attribute__((ext_vector_type(4), aligned(16)));
__device__ __forceinline__ f4a f4add(f4a a, f4a b) { return a + b; }

// global -> LDS direct (async DMA, no VGPR round-trip, no result registers ->
// the prefetch cannot be compiler-dropped). LDS dest wave-uniform + lane*16.
#define GLDS16(gp, lp)                                                        \
    __builtin_amdgcn_global_load_lds(                                         \
        (const __attribute__((address_space(1))) void*)(gp),                  \
        (__attribute__((address_space(3))) void*)(lp), 16, 0, 0)

// ---------------------------------------------------------------------------
// K1: R7's verified tile structure (TW=32, TH=8, raw GLDS stage, in-place
// D-chain, H-pass) in a persistent-block DOUBLE-BUFFERED pipeline.
// vmcnt accounting is PER-WAVE (R10 bug): each wave issues 6 GLDS + 4 stores
// per iteration. End-of-iter fence = s_waitcnt vmcnt(4): with in-order
// retirement, <=4 outstanding  =>  all 6 older prefetch loads have landed in
// LDS; only the 4 newest stores may remain in flight. (R10's vmcnt(8) only
// guaranteed 2 of 6 loads -> next phase A read a partially-filled buffer.)
//   iter: STAGE(nxt, tile t+1)            // 6 GLDS/wave, fire-and-forget
//         phase A on cur (in-place D-blur, verified chains)
//         s_waitcnt lgkmcnt(0); s_barrier // A's LDS writes visible
//         phase B on cur (verified H-pass + stores)
//         s_waitcnt vmcnt(4); s_barrier   // prefetch landed; stores in flight
// 768 blocks = 3/CU (2x24.6 KB LDS), 7 tiles each, XCD-chunked.
// Raw s_barrier (not __syncthreads) so no compiler vmcnt(0) drain.
// All sums / clamps / store addresses bit-identical to verified R7.
// ---------------------------------------------------------------------------
#define TILE_WORDS (DD * 12 * 32)     // 6144 floats = 24576 B per buffer
#define NB1   768                     // 3 blocks/CU x 256 CU
#define TPB   7                       // 5376 / 768 tiles per block

__device__ __forceinline__ void stage_tile(const float* __restrict__ mp,
                                           float* __restrict__ buf,
                                           int t, int wv, int lane) {
    const int yb = t & 31;
    const int wt = (t >> 5) & 7;
    const int ch = t >> 8;
    const int h0 = yb * 8;
    const float* __restrict__ src = mp + (size_t)ch * DHW + wt * 32;
#pragma unroll
    for (int j = 0; j < 6; ++j) {
        const int inst = wv * 6 + j;               // 0..23
        const int idx4 = inst * 64 + lane;         // vec4 index 0..1535
        const int d    = idx4 / 96;                // plane 0..15
        const int r    = idx4 - d * 96;
        const int py   = r >> 3;                   // 0..11
        const int x4   = r & 7;                    // 0..7
        const int h    = min(HH - 1, max(0, h0 + py - 2));
        GLDS16(src + (size_t)d * HWP + (size_t)h * WW + x4 * 4, buf + inst * 256);
    }
}

__global__ __launch_bounds__(256, 3) void dh_blur_kernel(const float* __restrict__ mp,
                                                         float* __restrict__ out) {
    __shared__ float A[2 * TILE_WORDS];   // 49152 B
    const int tid  = threadIdx.x;
    const int wv   = tid >> 6;
    const int lane = tid & 63;

    const int xcd  = blockIdx.x & 7;
    const int slot = blockIdx.x >> 3;     // 0..95
    const int tbase = xcd * 672 + slot;   // tiles tbase + it*96, it=0..6

    // prologue: stage tile 0 into buffer 0, full drain
    stage_tile(mp, A, tbase, wv, lane);
    asm volatile("s_waitcnt vmcnt(0)" ::: "memory");
    __builtin_amdgcn_s_barrier();

    for (int it = 0; it < TPB; ++it) {
        const int t  = tbase + it * 96;
        const int yb = t & 31;
        const int wt = (t >> 5) & 7;
        const int ch = t >> 8;
        const int w0 = wt * 32;
        const int h0 = yb * 8;
        float* const cur = A + (it & 1) * TILE_WORDS;
        float* const nxt = A + ((it & 1) ^ 1) * TILE_WORDS;

        // prefetch next tile into the other buffer (in flight across compute)
        if (it + 1 < TPB) stage_tile(mp, nxt, tbase + (it + 1) * 96, wv, lane);

        // ---- phase A: in-place D-blur per column (verified chains) ----
        if (tid < 96) {
            const int py = tid >> 3;              // 0..11
            const int x4 = tid & 7;               // quad 0..7
            float* colA = cur + py * 32 + x4 * 4; // + d*384

            f4a P[16];
#pragma unroll
            for (int d = 0; d < 16; ++d) P[d] = *(const f4a*)(colA + d * 384);

            constexpr int M0[12] = {0, 0, 0, 1, 2, 3, 4, 5, 6, 7, 8, 9};
            constexpr int M1[12] = {6, 7, 8, 9, 10, 11, 12, 13, 14, 15, 15, 15};

            {   // s = 0: planes 0..7
                f4a sum = f4add(f4add(f4add(P[M0[0]], P[M0[1]]),
                                      f4add(P[M0[2]], P[M0[3]])), P[M0[4]]);
#pragma unroll
                for (int i = 0; i < 8; ++i) {
                    *(f4a*)(colA + i * 384) = sum;
                    if (i < 7) sum = sum - P[M0[i]] + P[M0[i + 5]];
                }
            }
            {   // s = 1: planes 8..15
                f4a sum = f4add(f4add(f4add(P[M1[0]], P[M1[1]]),
                                      f4add(P[M1[2]], P[M1[3]])), P[M1[4]]);
#pragma unroll
                for (int i = 0; i < 8; ++i) {
                    *(f4a*)(colA + (8 + i) * 384) = sum;
                    if (i < 7) sum = sum - P[M1[i]] + P[M1[i + 5]];
                }
            }
        }
        asm volatile("s_waitcnt lgkmcnt(0)" ::: "memory");   // A's writes visible
        __builtin_amdgcn_s_barrier();

        // ---- phase B: verified H-pass + stores ----
#pragma unroll
        for (int it2 = 0; it2 < 4; ++it2) {
            const int tt   = tid + it2 * 256;
            const int xx4  = tt & 7;
            const int y    = (tt >> 3) & 7;
            const int dout = tt >> 6;

            const float* b = cur + dout * 384 + y * 32 + xx4 * 4;
            f4a a = *(const f4a*)b;
#pragma unroll
            for (int k = 1; k < 5; ++k) a = f4add(a, *(const f4a*)(b + k * 32));

            *(f4a*)(out + (size_t)ch * DHW + (size_t)dout * HWP
                    + (size_t)(h0 + y) * WW + w0 + xx4 * 4) = a;
        }

        // per-wave: 6 prefetch loads (older) + 4 stores (newer) outstanding.
        // vmcnt(4): all 6 loads retired (LDS valid); stores may stay in flight.
        asm volatile("s_waitcnt vmcnt(4)" ::: "memory");
        __builtin_amdgcn_s_barrier();
    }
}

// ---------------------------------------------------------------------------
// K2: W-blur + weighted-median, verbatim verified round-1 kernel (6.5 TB/s).
// ---------------------------------------------------------------------------
#define ROWP 264   // 2 pad + 2 lo-edge + 256 data + 2 hi-edge + 2 pad

__global__ __launch_bounds__(256) void wmedian_kernel(float* __restrict__ y4) {
    __shared__ float R[CC * ROWP];

    const int h = blockIdx.x;
    const int d = blockIdx.y;
    const int tid = threadIdx.x;
    float* __restrict__ base = y4 + (size_t)d * HWP + (size_t)h * WW;

    for (int idx = tid; idx < CC * 64; idx += 256) {
        const int c  = idx >> 6;
        const int w4 = idx & 63;
        *(f4a*)(&R[c * ROWP + 4 + w4 * 4]) = *(const f4a*)(base + (size_t)c * DHW + w4 * 4);
    }
    if (tid < CC) {
        const float v0 = base[(size_t)tid * DHW];
        const float vL = base[(size_t)tid * DHW + (WW - 1)];
        R[tid * ROWP + 2]   = v0;
        R[tid * ROWP + 3]   = v0;
        R[tid * ROWP + 260] = vL;
        R[tid * ROWP + 261] = vL;
    }
    __syncthreads();

    const int w = tid;   // 0..255
    float v[CC];
    float tot = 0.f;
#pragma unroll
    for (int c = 0; c < CC; ++c) {
        const float* r = &R[c * ROWP + 2 + w];           // r[0] = value at w-2
        v[c] = ((((r[0] + r[1]) + r[2]) + r[3]) + r[4]); // verified W order
        tot += v[c];
    }
    const float inv = 1.0f / tot;

    float s = 0.f, sv0 = 0.f, sv1 = 0.f;
    int m0 = 0, m1 = 0;
#pragma unroll
    for (int c = 0; c < CC; ++c) {
        const float yn = v[c] * inv;
        const float sn = s + yn;
        if (c == 0) { sv0 = yn; sv1 = yn; }                           // defaults
        if (v[c] > 0.f && sn < 0.5f) { m0 = c; sv0 = yn; }            // last qualifying
        if (m1 == 0 && c > 0 && sn > 0.5f) { m1 = c; sv1 = yn; }      // first qualifying
        s = sn;
    }

#pragma unroll
    for (int c = 0; c < CC; ++c) {
        base[(size_t)c * DHW + w] = (c == m0) ? sv0 : ((c == m1) ? sv1 : 0.f);
    }
}

extern "C" void kernel_launch(void* const* d_in, const int* in_sizes, int n_in,
                              void* d_out, int out_size, void* d_ws, size_t ws_size,
                              hipStream_t stream) {
    const float* mp = (const float*)d_in[0];
    float* out = (float*)d_out;

    dh_blur_kernel<<<NB1, 256, 0, stream>>>(mp, out);       // 768 persistent, pipelined
    wmedian_kernel<<<dim3(HH, DD), 256, 0, stream>>>(out);  // 4096 blocks
}